// Round 6
// baseline (51.492 us; speedup 1.0000x reference)
//
#include <hip/hip_runtime.h>
#include <hip/hip_bf16.h>
#include <stdint.h>

// out[n,f,i,j] = sum_k W[f,k]*patch[n,i,j,k] - 0.5||W_f||^2 - 0.5||X_{n,i,j}||^2
// x: (32,128,28,28) f32 ; W: (128,128,3,3) f32 ; out: (32,128,30,30) f32
// pad=2, ho=wo=30, L=28800, K=1152, F=128

#define N_IMG 32
#define C_IN 128
#define H_IN 28
#define HP 32
#define HO 30
#define P_SP 900
#define L_TOT (P_SP*N_IMG)  // 28800
#define F_OUT 128
#define K_TOT 1152

#define BLT 64              // L-tile per block
#define NBLK (L_TOT/BLT)    // 450 blocks x 128 threads (2 waves of 64f x 64L)

typedef __attribute__((ext_vector_type(8))) short bf16x8;
typedef __attribute__((ext_vector_type(8))) unsigned short u16x8;
typedef __attribute__((ext_vector_type(4))) float f32x4;

__device__ __forceinline__ unsigned short f2bf(float f) {
  union { float f; unsigned u; } t; t.f = f;
  unsigned r = t.u + 0x7fffu + ((t.u >> 16) & 1u);
  return (unsigned short)(r >> 16);
}

// ---------------------------------------------------------------------------
// Kernel 1: fused prep (r4-proven). Blocks 0..1023: pad+convert x ->
// channels-last bf16 xcl[n][hp][wp][c] (16B stores) + per-pixel f32 squared
// sums s[n][hp][wp]. Blocks 1024..1151: W -> bf16 reordered k' = rr*128+ch,
// + wnorm[f] = 0.5||W_f||^2.
// ---------------------------------------------------------------------------
__global__ void prep_xw_kernel(const float* __restrict__ x,
                               const float* __restrict__ W,
                               unsigned short* __restrict__ xcl,
                               float* __restrict__ s,
                               unsigned short* __restrict__ Wbf,
                               float* __restrict__ wnorm) {
  int bid = blockIdx.x;
  if (bid < N_IMG * HP) {
    int n = bid >> 5, hp = bid & 31;
    __shared__ float rowT[H_IN * C_IN];   // [w][c], 14336 B
    bool interior = (hp >= 2 && hp < 2 + H_IN);
    int h = hp - 2;
    if (interior) {
      for (int idx = threadIdx.x; idx < C_IN * 7; idx += 256) {
        int c = idx / 7, w4 = (idx - c * 7) * 4;
        const float* xp = x + ((n * C_IN + c) * H_IN + h) * H_IN + w4;
        float4 v = *(const float4*)xp;
        rowT[(w4 + 0) * C_IN + c] = v.x;
        rowT[(w4 + 1) * C_IN + c] = v.y;
        rowT[(w4 + 2) * C_IN + c] = v.z;
        rowT[(w4 + 3) * C_IN + c] = v.w;
      }
    }
    __syncthreads();
    for (int idx = threadIdx.x; idx < HP * 16; idx += 256) {
      int wp = idx >> 4, c8 = (idx & 15) * 8;
      u16x8 o;
#pragma unroll
      for (int q = 0; q < 8; q++) o[q] = 0;
      if (interior && wp >= 2 && wp < 2 + H_IN) {
        const float* rp = &rowT[(wp - 2) * C_IN + c8];
#pragma unroll
        for (int q = 0; q < 8; q++) o[q] = (short)f2bf(rp[q]);
      }
      *(u16x8*)(&xcl[((n * HP + hp) * HP + wp) * C_IN + c8]) = o;
    }
    int wp = threadIdx.x >> 3, l8 = threadIdx.x & 7;
    float sum = 0.f;
    if (interior && wp >= 2 && wp < 2 + H_IN) {
      const float* rp = &rowT[(wp - 2) * C_IN];
      for (int c = l8; c < C_IN; c += 8) { float v = rp[c]; sum += v * v; }
    }
    sum += __shfl_down(sum, 4, 8);
    sum += __shfl_down(sum, 2, 8);
    sum += __shfl_down(sum, 1, 8);
    if (l8 == 0) s[(n * HP + hp) * HP + wp] = sum;
  } else {
    int f = bid - N_IMG * HP;
    const float* Wf = W + f * K_TOT;
    float part = 0.f;
    for (int k = threadIdx.x; k < K_TOT; k += 256) {
      float v = Wf[k];                 // k = ch*9 + rr
      part += v * v;
      int ch = k / 9, rr = k - ch * 9;
      Wbf[f * K_TOT + rr * 128 + ch] = f2bf(v);
    }
    __shared__ float red[256];
    red[threadIdx.x] = part;
    __syncthreads();
    for (int st = 128; st > 0; st >>= 1) {
      if (threadIdx.x < st) red[threadIdx.x] += red[threadIdx.x + st];
      __syncthreads();
    }
    if (threadIdx.x == 0) wnorm[f] = 0.5f * red[0];
  }
}

// ---------------------------------------------------------------------------
// Kernel 2: register-direct implicit-im2col GEMM. NO LDS, NO barriers in the
// K-loop: A (Wbf) and B (xcl) fragments load straight from L1/L2 into VGPRs
// (16-lane x 64B contiguous segments per instruction). Everything is
// L3-resident; Wbf rows are shared by all co-resident blocks -> L1 hits.
// Block = 128 threads = 2 waves; wave = 64f x 64L, acc[4][4] (16x16x32 bf16,
// 2 MFMA per 16B load). Fully unrolled rr(9) x kc(4): all A offsets are
// compile-time immediates off 4 static bases; B advances per-rr by constant
// deltas. Epilogue: LDS transpose -> 256B-coalesced nontemporal stores with
// fused -wnorm[f] - 0.5||X||^2.
// ---------------------------------------------------------------------------
__global__ __launch_bounds__(128, 2) void adder_gemm_kernel(
    const unsigned short* __restrict__ Wbf,
    const unsigned short* __restrict__ xcl,
    const float* __restrict__ wnorm,
    const float* __restrict__ s,
    float* __restrict__ out) {
  __shared__ float Cst[F_OUT * 65];   // 33280 B
  __shared__ float xn_s[BLT];
  __shared__ float wn_s[F_OUT];

  int tid = threadIdx.x, lane = tid & 63, wid = tid >> 6;   // 2 waves: f-halves
  int L0 = blockIdx.x * BLT;
  int colc = lane & 15, kg = lane >> 4;   // fragment row/col + k-group

  // A bases: row = wid*64 + mi*16 + colc, byte = row*2304 + kg*16
  const char* WbfB = (const char*)Wbf;
  const char* Ab[4];
#pragma unroll
  for (int mi = 0; mi < 4; mi++)
    Ab[mi] = WbfB + (size_t)(wid * 64 + mi * 16 + colc) * (K_TOT * 2) + kg * 16;

  // B bases: col cc = ni*16 + colc -> l = L0+cc -> padded pixel (n, i, j);
  // byte = ((n*32 + i)*32 + j)*256 + kg*16 ; per-rr add (dh*32+dw)*256.
  const char* xclB = (const char*)xcl;
  const char* Bb[4];
#pragma unroll
  for (int ni = 0; ni < 4; ni++) {
    int l = L0 + ni * 16 + colc;
    int n = l / P_SP, p = l - n * P_SP, i = p / HO, j = p - i * HO;
    Bb[ni] = xclB + (size_t)((n * HP + i) * HP + j) * (C_IN * 2) + kg * 16;
  }

  f32x4 acc[4][4];
#pragma unroll
  for (int mi = 0; mi < 4; mi++)
#pragma unroll
    for (int ni = 0; ni < 4; ni++)
      acc[mi][ni] = (f32x4){0.f, 0.f, 0.f, 0.f};

#pragma unroll
  for (int rr = 0; rr < 9; rr++) {
    const int dh = rr / 3, dw = rr - 3 * dh;
    const int aoff = rr * 256;                  // A k'-slice (<= 2048, imm-able)
    const int boff = (dh * HP + dw) * 256;      // B window shift (compile-time)
#pragma unroll
    for (int kc = 0; kc < 4; kc++) {
      bf16x8 af[4], bfv[4];
#pragma unroll
      for (int mi = 0; mi < 4; mi++)
        af[mi] = *(const bf16x8*)(Ab[mi] + aoff + kc * 64);
#pragma unroll
      for (int ni = 0; ni < 4; ni++)
        bfv[ni] = *(const bf16x8*)(Bb[ni] + boff + kc * 64);
#pragma unroll
      for (int mi = 0; mi < 4; mi++)
#pragma unroll
        for (int ni = 0; ni < 4; ni++)
          acc[mi][ni] = __builtin_amdgcn_mfma_f32_16x16x32_bf16(
              af[mi], bfv[ni], acc[mi][ni], 0, 0, 0);
    }
  }

  // ---- epilogue ----
  if (tid < BLT) {
    int l = L0 + tid;
    int n = l / P_SP, p = l - n * P_SP, i = p / HO, j = p - i * HO;
    const float* sn = s + n * (HP * HP);
    float a9 = 0.f;
#pragma unroll
    for (int dh = 0; dh < 3; dh++)
#pragma unroll
      for (int dw = 0; dw < 3; dw++)
        a9 += sn[(i + dh) * HP + (j + dw)];
    xn_s[tid] = 0.5f * a9;
  }
  if (tid < F_OUT) wn_s[tid] = wnorm[tid];
  // acc -> LDS: f = wid*64 + mi*16 + kg*4 + r ; col = ni*16 + colc
#pragma unroll
  for (int mi = 0; mi < 4; mi++) {
    int f0 = wid * 64 + mi * 16 + kg * 4;
#pragma unroll
    for (int ni = 0; ni < 4; ni++) {
      int cc = ni * 16 + colc;
#pragma unroll
      for (int r = 0; r < 4; r++)
        Cst[(f0 + r) * 65 + cc] = acc[mi][ni][r];
    }
  }
  __syncthreads();
  // coalesced nontemporal stores: 64 lanes = 64 consecutive cols (256 B)
  {
    int col = tid & 63, fh = tid >> 6;
    int l = L0 + col;
    int n = l / P_SP, p = l - n * P_SP;
    float* ob = out + (size_t)n * (F_OUT * P_SP) + p;
    float xn = xn_s[col];
#pragma unroll
    for (int q = 0; q < 64; q++) {
      int f = q * 2 + fh;
      __builtin_nontemporal_store(Cst[f * 65 + col] - wn_s[f] - xn, ob + f * P_SP);
    }
  }
}

// ---------------------------------------------------------------------------
extern "C" void kernel_launch(void* const* d_in, const int* in_sizes, int n_in,
                              void* d_out, int out_size, void* d_ws, size_t ws_size,
                              hipStream_t stream) {
  const float* x = (const float*)d_in[0];
  const float* W = (const float*)d_in[1];
  float* out = (float*)d_out;

  char* ws = (char*)d_ws;
  unsigned short* xcl = (unsigned short*)(ws);                   // 8,388,608 B
  unsigned short* Wbf = (unsigned short*)(ws + 8388608);         //   294,912 B
  float* wnorm = (float*)(ws + 8683520);                         //       512 B
  float* s     = (float*)(ws + 8684032);                         //   131,072 B

  prep_xw_kernel<<<N_IMG * HP + F_OUT, 256, 0, stream>>>(x, W, xcl, s, Wbf, wnorm);
  adder_gemm_kernel<<<NBLK, 128, 0, stream>>>(Wbf, xcl, wnorm, s, out);
}

// Round 7
// 41.173 us; speedup vs baseline: 1.2506x; 1.2506x over previous
//
#include <hip/hip_runtime.h>
#include <hip/hip_bf16.h>
#include <stdint.h>

// out[n,f,i,j] = sum_k W[f,k]*patch[n,i,j,k] - 0.5||W_f||^2 - 0.5||X_{n,i,j}||^2
// x: (32,128,28,28) f32 ; W: (128,128,3,3) f32 ; out: (32,128,30,30) f32
// pad=2, ho=wo=30, L=28800, K=1152, F=128

#define N_IMG 32
#define C_IN 128
#define H_IN 28
#define HP 32
#define HO 30
#define P_SP 900
#define L_TOT (P_SP*N_IMG)  // 28800
#define F_OUT 128
#define K_TOT 1152

#define BLT 128             // block L-tile
#define NBLK (L_TOT/BLT)    // 225 blocks x 256 threads (4 waves, each 64F x 64L)
#define NSTEP 18            // K steps of BK=64 (9 window positions x 2 halves)

typedef __attribute__((ext_vector_type(8))) short bf16x8;
typedef __attribute__((ext_vector_type(8))) unsigned short u16x8;
typedef __attribute__((ext_vector_type(4))) float f32x4;

__device__ __forceinline__ unsigned short f2bf(float f) {
  union { float f; unsigned u; } t; t.f = f;
  unsigned r = t.u + 0x7fffu + ((t.u >> 16) & 1u);
  return (unsigned short)(r >> 16);
}

// ---------------------------------------------------------------------------
// Kernel 1: fused prep (proven r4). Blocks 0..1023: pad+convert x ->
// channels-last bf16 xcl[n][hp][wp][c] (16B stores) + per-pixel f32 squared
// sums s[n][hp][wp]. Blocks 1024..1151: W -> bf16 reordered k' = rr*128+ch,
// + wnorm[f] = 0.5||W_f||^2.
// ---------------------------------------------------------------------------
__global__ void prep_xw_kernel(const float* __restrict__ x,
                               const float* __restrict__ W,
                               unsigned short* __restrict__ xcl,
                               float* __restrict__ s,
                               unsigned short* __restrict__ Wbf,
                               float* __restrict__ wnorm) {
  int bid = blockIdx.x;
  if (bid < N_IMG * HP) {
    int n = bid >> 5, hp = bid & 31;
    __shared__ float rowT[H_IN * C_IN];   // [w][c], 14336 B
    bool interior = (hp >= 2 && hp < 2 + H_IN);
    int h = hp - 2;
    if (interior) {
      for (int idx = threadIdx.x; idx < C_IN * 7; idx += 256) {
        int c = idx / 7, w4 = (idx - c * 7) * 4;
        const float* xp = x + ((n * C_IN + c) * H_IN + h) * H_IN + w4;
        float4 v = *(const float4*)xp;
        rowT[(w4 + 0) * C_IN + c] = v.x;
        rowT[(w4 + 1) * C_IN + c] = v.y;
        rowT[(w4 + 2) * C_IN + c] = v.z;
        rowT[(w4 + 3) * C_IN + c] = v.w;
      }
    }
    __syncthreads();
    for (int idx = threadIdx.x; idx < HP * 16; idx += 256) {
      int wp = idx >> 4, c8 = (idx & 15) * 8;
      u16x8 o;
#pragma unroll
      for (int q = 0; q < 8; q++) o[q] = 0;
      if (interior && wp >= 2 && wp < 2 + H_IN) {
        const float* rp = &rowT[(wp - 2) * C_IN + c8];
#pragma unroll
        for (int q = 0; q < 8; q++) o[q] = (short)f2bf(rp[q]);
      }
      *(u16x8*)(&xcl[((n * HP + hp) * HP + wp) * C_IN + c8]) = o;
    }
    int wp = threadIdx.x >> 3, l8 = threadIdx.x & 7;
    float sum = 0.f;
    if (interior && wp >= 2 && wp < 2 + H_IN) {
      const float* rp = &rowT[(wp - 2) * C_IN];
      for (int c = l8; c < C_IN; c += 8) { float v = rp[c]; sum += v * v; }
    }
    sum += __shfl_down(sum, 4, 8);
    sum += __shfl_down(sum, 2, 8);
    sum += __shfl_down(sum, 1, 8);
    if (l8 == 0) s[(n * HP + hp) * HP + wp] = sum;
  } else {
    int f = bid - N_IMG * HP;
    const float* Wf = W + f * K_TOT;
    float part = 0.f;
    for (int k = threadIdx.x; k < K_TOT; k += 256) {
      float v = Wf[k];                 // k = ch*9 + rr
      part += v * v;
      int ch = k / 9, rr = k - ch * 9;
      Wbf[f * K_TOT + rr * 128 + ch] = f2bf(v);
    }
    __shared__ float red[256];
    red[threadIdx.x] = part;
    __syncthreads();
    for (int st = 128; st > 0; st >>= 1) {
      if (threadIdx.x < st) red[threadIdx.x] += red[threadIdx.x + st];
      __syncthreads();
    }
    if (threadIdx.x == 0) wnorm[f] = 0.5f * red[0];
  }
}

// ---------------------------------------------------------------------------
// Kernel 2: implicit-im2col GEMM, balanced 64x64 wave tiles + counted-vmcnt
// double-buffered pipeline (T3/T4/T5).
// Block tile 128F x 128L, BK=64, 18 steps. 4 waves (2x2), each 64x64:
// 16 ds_read_b128 per 32 MFMA = 32 FLOP/LDS-byte (above the ~30 balance
// point -> MFMA is the pole, not the LDS port). Per step:
//   COMPUTE(t) -> barrier -> STAGE(t+2 into just-freed buffer) ->
//   s_waitcnt vmcnt(8)  (waits STAGE(t+1), leaves t+2's 8 in flight) ->
//   barrier.  vmcnt never drains to 0 in the main loop.
// LDS rows 128 B k-contiguous, XOR swizzle byte ^= ((row&7)<<4): linear
// global_load_lds dest + inverse-swizzled global source + swizzled ds_read.
// ---------------------------------------------------------------------------
__global__ __launch_bounds__(256, 2) void adder_gemm_kernel(
    const unsigned short* __restrict__ Wbf,
    const unsigned short* __restrict__ xcl,
    const float* __restrict__ wnorm,
    const float* __restrict__ s,
    float* __restrict__ out) {
  __shared__ unsigned short A_lds[2][128 * 64];   // 2 x 16 KB (128 rows x 128 B)
  __shared__ unsigned short B_lds[2][128 * 64];   // 2 x 16 KB
  __shared__ float wn_s[F_OUT];

  int tid = threadIdx.x, lane = tid & 63, wid = tid >> 6;
  int wr = wid >> 1, wc = wid & 1;
  int L0 = blockIdx.x * BLT;

  const char* WbfB = (const char*)Wbf;
  const char* xclB = (const char*)xcl;

  // Staging: 16 chunks of 1KB per tile (8 rows x 128B each); chunk q done by
  // wave wid=q&3 slot a=q>>2. Within chunk: row = lane>>3, byte = (lane&7)*16.
  // Physical LDS [row][b] holds logical k-byte (b ^ ((row&7)<<4)).
  int kb = ((lane & 7) * 16) ^ ((lane >> 3) << 4);   // pre-swizzled source byte
  int a_goff[4], b_goff[4];
#pragma unroll
  for (int a = 0; a < 4; a++) {
    int q = a * 4 + wid;
    int row = q * 8 + (lane >> 3);                   // 0..127
    a_goff[a] = row * (K_TOT * 2) + kb;              // + rr*256 + half*128
    int l = L0 + row;
    int n = l / P_SP, p = l - n * P_SP, i = p / HO, j = p - i * HO;
    b_goff[a] = ((n * HP + i) * HP + j) * (C_IN * 2) + kb; // + (dh*32+dw)*256 + half*128
  }

  auto STAGE = [&](int t, int bufi) {
    int rr = t >> 1, half = t & 1;
    int aoff = rr * 256 + half * 128;
    int boff = ((rr / 3) * HP + (rr % 3)) * (C_IN * 2) + half * 128;
    char* AB = (char*)(&A_lds[bufi][0]);
    char* BB = (char*)(&B_lds[bufi][0]);
#pragma unroll
    for (int a = 0; a < 4; a++)
      __builtin_amdgcn_global_load_lds(
          (const __attribute__((address_space(1))) void*)(WbfB + a_goff[a] + aoff),
          (__attribute__((address_space(3))) void*)(AB + (a * 4 + wid) * 1024 + lane * 16),
          16, 0, 0);
#pragma unroll
    for (int a = 0; a < 4; a++)
      __builtin_amdgcn_global_load_lds(
          (const __attribute__((address_space(1))) void*)(xclB + b_goff[a] + boff),
          (__attribute__((address_space(3))) void*)(BB + (a * 4 + wid) * 1024 + lane * 16),
          16, 0, 0);
  };

  f32x4 acc[4][4];
#pragma unroll
  for (int mi = 0; mi < 4; mi++)
#pragma unroll
    for (int ni = 0; ni < 4; ni++)
      acc[mi][ni] = (f32x4){0.f, 0.f, 0.f, 0.f};

  // Prologue: prefetch steps 0 (buf0) and 1 (buf1); wait only for step 0.
  STAGE(0, 0);
  STAGE(1, 1);
  if (tid < F_OUT) wn_s[tid] = wnorm[tid];
  asm volatile("s_waitcnt vmcnt(8)" ::: "memory");
  __builtin_amdgcn_s_barrier();

  int kfrag = (lane >> 4) * 16;
  for (int t = 0; t < NSTEP; t++) {
    int cur = t & 1;
    const char* AB = (const char*)(&A_lds[cur][0]);
    const char* BB = (const char*)(&B_lds[cur][0]);
#pragma unroll
    for (int kc = 0; kc < 2; kc++) {
      bf16x8 af[4], bfv[4];
#pragma unroll
      for (int mi = 0; mi < 4; mi++) {
        int rowf = wr * 64 + mi * 16 + (lane & 15);
        af[mi] = *(const bf16x8*)(AB + rowf * 128 + ((kc * 64 + kfrag) ^ ((rowf & 7) << 4)));
      }
#pragma unroll
      for (int ni = 0; ni < 4; ni++) {
        int cc = wc * 64 + ni * 16 + (lane & 15);
        bfv[ni] = *(const bf16x8*)(BB + cc * 128 + ((kc * 64 + kfrag) ^ ((cc & 7) << 4)));
      }
      __builtin_amdgcn_s_setprio(1);
#pragma unroll
      for (int mi = 0; mi < 4; mi++)
#pragma unroll
        for (int ni = 0; ni < 4; ni++)
          acc[mi][ni] = __builtin_amdgcn_mfma_f32_16x16x32_bf16(
              af[mi], bfv[ni], acc[mi][ni], 0, 0, 0);
      __builtin_amdgcn_s_setprio(0);
    }
    // all waves done READING buf[cur] (MFMA consumption forced lgkm waits)
    __builtin_amdgcn_s_barrier();
    if (t + 2 < NSTEP) {
      STAGE(t + 2, cur);                              // refill just-freed buffer
      asm volatile("s_waitcnt vmcnt(8)" ::: "memory"); // STAGE(t+1) landed;
      __builtin_amdgcn_s_barrier();                    // t+2's 8 stay in flight
    } else if (t + 1 < NSTEP) {
      asm volatile("s_waitcnt vmcnt(0)" ::: "memory"); // tail drain for step 17
      __builtin_amdgcn_s_barrier();
    }
  }

  // ---- Epilogue: fused norms, direct stores (16-lane x 4B = 64B segments) ----
#pragma unroll
  for (int ni = 0; ni < 4; ni++) {
    int cc = wc * 64 + ni * 16 + (lane & 15);
    int l = L0 + cc;
    int n = l / P_SP, p = l - n * P_SP, i = p / HO, j = p - i * HO;
    const float* sn = s + n * (HP * HP);
    float a9 = 0.f;
#pragma unroll
    for (int dh = 0; dh < 3; dh++)
#pragma unroll
      for (int dw = 0; dw < 3; dw++)
        a9 += sn[(i + dh) * HP + (j + dw)];
    float xn = 0.5f * a9;
    float* ob = out + (size_t)n * (F_OUT * P_SP) + p;
#pragma unroll
    for (int mi = 0; mi < 4; mi++) {
      int f0 = wr * 64 + mi * 16 + (lane >> 4) * 4;
#pragma unroll
      for (int r2 = 0; r2 < 4; r2++) {
        int f = f0 + r2;
        __builtin_nontemporal_store(acc[mi][ni][r2] - wn_s[f] - xn, ob + f * P_SP);
      }
    }
  }
}

// ---------------------------------------------------------------------------
extern "C" void kernel_launch(void* const* d_in, const int* in_sizes, int n_in,
                              void* d_out, int out_size, void* d_ws, size_t ws_size,
                              hipStream_t stream) {
  const float* x = (const float*)d_in[0];
  const float* W = (const float*)d_in[1];
  float* out = (float*)d_out;

  char* ws = (char*)d_ws;
  unsigned short* xcl = (unsigned short*)(ws);                   // 8,388,608 B
  unsigned short* Wbf = (unsigned short*)(ws + 8388608);         //   294,912 B
  float* wnorm = (float*)(ws + 8683520);                         //       512 B
  float* s     = (float*)(ws + 8684032);                         //   131,072 B

  prep_xw_kernel<<<N_IMG * HP + F_OUT, 256, 0, stream>>>(x, W, xcl, s, Wbf, wnorm);
  adder_gemm_kernel<<<NBLK, 256, 0, stream>>>(Wbf, xcl, wnorm, s, out);
}

// Round 8
// 33.366 us; speedup vs baseline: 1.5433x; 1.2340x over previous
//
#include <hip/hip_runtime.h>
#include <hip/hip_bf16.h>
#include <stdint.h>

// out[n,f,i,j] = sum_k W[f,k]*patch[n,i,j,k] - 0.5||W_f||^2 - 0.5||X_{n,i,j}||^2
// x: (32,128,28,28) f32 ; W: (128,128,3,3) f32 ; out: (32,128,30,30) f32
// pad=2, ho=wo=30, L=28800, K=1152, F=128

#define N_IMG 32
#define C_IN 128
#define H_IN 28
#define HP 32
#define HO 30
#define P_SP 900
#define F_OUT 128
#define K_TOT 1152

#define BLT 60              // L-tile: 2 raster rows, no image crossing
#define TPI 15              // tiles per image
#define NBLK (N_IMG*TPI)    // 480 blocks; 49.3 KB LDS -> 3 blocks/CU (12 waves/CU)
#define NSTEP 36            // K steps of BK=32 (9 window positions x 4 quarters)

typedef __attribute__((ext_vector_type(8))) short bf16x8;
typedef __attribute__((ext_vector_type(4))) unsigned short u16x4;
typedef __attribute__((ext_vector_type(8))) unsigned short u16x8;
typedef __attribute__((ext_vector_type(4))) float f32x4;

__device__ __forceinline__ unsigned short f2bf(float f) {
  union { float f; unsigned u; } t; t.f = f;
  unsigned r = t.u + 0x7fffu + ((t.u >> 16) & 1u);
  return (unsigned short)(r >> 16);
}

// ---------------------------------------------------------------------------
// Kernel 1 (tiny): W -> bf16 reordered k' = rr*128 + ch, + wnorm = 0.5||W_f||^2
// ---------------------------------------------------------------------------
__global__ void prep_w_kernel(const float* __restrict__ W,
                              unsigned short* __restrict__ Wbf,
                              float* __restrict__ wnorm) {
  int f = blockIdx.x;
  const float* Wf = W + f * K_TOT;
  float part = 0.f;
  for (int k = threadIdx.x; k < K_TOT; k += 256) {
    float v = Wf[k];                 // k = ch*9 + rr
    part += v * v;
    int ch = k / 9, rr = k - ch * 9;
    Wbf[f * K_TOT + rr * 128 + ch] = f2bf(v);
  }
  __shared__ float red[256];
  red[threadIdx.x] = part;
  __syncthreads();
  for (int st = 128; st > 0; st >>= 1) {
    if (threadIdx.x < st) red[threadIdx.x] += red[threadIdx.x + st];
    __syncthreads();
  }
  if (threadIdx.x == 0) wnorm[f] = 0.5f * red[0];
}

// ---------------------------------------------------------------------------
// Kernel 2: fused x-prep + implicit-im2col GEMM (r5 structure + 3 fixes).
//  - xfoot: block's unique x pixels (4 padded rows x 32 x 128c) in LDS bf16,
//    swizzle byte ^= ((pix&15)<<4); 9x window reuse comes from LDS, not L2/L3.
//  - A-stream: BK=32 tiles (8 KB, 128 f-rows x 64 B), double-buffered via
//    global_load_lds; counted s_waitcnt vmcnt(2) (never 0 mid-loop).
//    A-row swizzle: phys = row*64 + (kb ^ ((row&3)<<4)).
//  - 49.3 KB LDS -> 3 blocks/CU -> 12 waves/CU (3/SIMD) of latency cover.
//  - Epilogue: acc -> Cst (aliases dead xfoot, [128][64] f32) -> 240-B
//    coalesced nontemporal stores, fused -wnorm[f] - 0.5||X||^2.
// ---------------------------------------------------------------------------
__global__ __launch_bounds__(256, 3) void adder_fused_kernel(
    const float* __restrict__ x,
    const unsigned short* __restrict__ Wbf,
    const float* __restrict__ wnorm,
    float* __restrict__ out) {
  __shared__ unsigned short xfoot[128 * 128];    // 32 KB (also epilogue Cst)
  __shared__ unsigned short A_lds[2][128 * 32];  // 2 x 8 KB (128 rows x 64 B)
  __shared__ float pixsum_s[128];
  __shared__ float xn_s[BLT];
  __shared__ float wn_s[F_OUT];

  int tid = threadIdx.x, lane = tid & 63, wid = tid >> 6;
  int bid = blockIdx.x;
  int n = bid / TPI, timg = bid - n * TPI;
  int i0 = timg * 2, p0 = timg * BLT;

  char* XF = (char*)xfoot;
  const char* WbfB = (const char*)Wbf;

  // ---- A staging addresses: tile = 8 chunks of 1KB (16 rows x 64 B each);
  // wave wid handles chunks {wid, wid+4}. lane l: row = q*16 + (l>>2),
  // phys byte = (l&3)*16, logical kb = phys ^ ((row&3)<<4).
  int kbl = (((lane & 3) ^ ((lane >> 2) & 3)) << 4);
  int a_goff[2], a_loff[2];
#pragma unroll
  for (int a = 0; a < 2; a++) {
    int q = a * 4 + wid;
    int row = q * 16 + (lane >> 2);
    a_goff[a] = row * (K_TOT * 2) + kbl;          // + rr*256 + qt*64 per step
    a_loff[a] = q * 1024 + lane * 16;
  }

  auto STAGE = [&](int rr, int qt, int bufi) {
    int off = rr * 256 + qt * 64;
    char* AB = (char*)(&A_lds[bufi][0]);
#pragma unroll
    for (int a = 0; a < 2; a++)
      __builtin_amdgcn_global_load_lds(
          (const __attribute__((address_space(1))) void*)(WbfB + a_goff[a] + off),
          (__attribute__((address_space(3))) void*)(AB + a_loff[a]), 16, 0, 0);
  };

  // ---- prologue: kick off A(step 0) DMA, then build xfoot ----
  STAGE(0, 0, 0);
  if (tid < F_OUT) wn_s[tid] = wnorm[tid];

  // x conversion: 4 padded rows (hr = i0-2+r), channels-last bf16, swizzled.
  for (int u = tid; u < 896; u += 256) {
    int r = u / 224, rem = u - r * 224;
    int w4 = rem >> 5, cq = rem & 31, c = cq * 4;
    int hr = i0 - 2 + r;
    float vv[4][4];
    if (hr >= 0 && hr < H_IN) {
#pragma unroll
      for (int q = 0; q < 4; q++) {
        float4 t4 = *(const float4*)(x + (((n * C_IN + c + q) * H_IN + hr) * H_IN + w4 * 4));
        vv[q][0] = t4.x; vv[q][1] = t4.y; vv[q][2] = t4.z; vv[q][3] = t4.w;
      }
    } else {
#pragma unroll
      for (int q = 0; q < 4; q++)
#pragma unroll
        for (int e = 0; e < 4; e++) vv[q][e] = 0.f;
    }
#pragma unroll
    for (int e = 0; e < 4; e++) {
      int wp = w4 * 4 + e + 2;            // 2..29
      int pix = r * 32 + wp;
      u16x4 o;
#pragma unroll
      for (int q = 0; q < 4; q++) o[q] = f2bf(vv[q][e]);
      *(u16x4*)(XF + pix * 256 + ((c * 2) ^ ((pix & 15) << 4))) = o;
    }
  }
  // border zeros: wp in {0,1,30,31} for all 4 rows
  {
    int r = tid >> 6, wi = (tid >> 4) & 3, slot = tid & 15;
    int wp = (wi < 2) ? wi : 28 + wi;     // 0,1,30,31
    int pix = r * 32 + wp;
    u16x8 z;
#pragma unroll
    for (int q = 0; q < 8; q++) z[q] = 0;
    *(u16x8*)(XF + pix * 256 + ((slot * 16) ^ ((pix & 15) << 4))) = z;
  }
  __syncthreads();

  // per-pixel squared channel sums (2 threads per pixel)
  {
    int pix = tid >> 1, ch = tid & 1;
    float ssum = 0.f;
#pragma unroll
    for (int q = 0; q < 8; q++) {
      u16x8 v8 = *(const u16x8*)(XF + pix * 256 + (((ch * 128) + q * 16) ^ ((pix & 15) << 4)));
#pragma unroll
      for (int e = 0; e < 8; e++) {
        union { unsigned u; float f; } cv; cv.u = ((unsigned)v8[e]) << 16;
        ssum += cv.f * cv.f;
      }
    }
    ssum += __shfl_xor(ssum, 1);
    if (!ch) pixsum_s[pix] = ssum;
  }
  __syncthreads();
  if (tid < BLT) {
    int il = tid / HO, j = tid - il * HO;
    float a9 = 0.f;
#pragma unroll
    for (int dh = 0; dh < 3; dh++)
#pragma unroll
      for (int dw = 0; dw < 3; dw++)
        a9 += pixsum_s[(il + dh) * 32 + (j + dw)];
    xn_s[tid] = 0.5f * a9;
  }
  __syncthreads();   // also drains STAGE(0) (landed long ago)

  // ---- K-loop ----
  f32x4 acc[4][2];
#pragma unroll
  for (int mi = 0; mi < 4; mi++)
#pragma unroll
    for (int ni = 0; ni < 2; ni++)
      acc[mi][ni] = (f32x4){0.f, 0.f, 0.f, 0.f};

  int wr = wid >> 1, wc = wid & 1;
  int colc = lane & 15, kg = lane >> 4;
  int pix0[2];
#pragma unroll
  for (int ni = 0; ni < 2; ni++) {
    int cc = wc * 32 + ni * 16 + colc;
    if (cc > BLT - 1) cc = BLT - 1;       // dead cols: valid reads, dropped later
    int il = cc / HO, j = cc - il * HO;
    pix0[ni] = il * 32 + j;
  }
  int asw = (colc & 3) << 4;              // A read swizzle for this lane's rows

  for (int rr2 = 0; rr2 < 9; rr2++) {
#pragma unroll 4
    for (int qt = 0; qt < 4; qt++) {
      int t = rr2 * 4 + qt;
      int cur = qt & 1;
      if (t + 1 < NSTEP) {
        int rn = (qt == 3) ? rr2 + 1 : rr2, qn = (qt + 1) & 3;
        STAGE(rn, qn, cur ^ 1);
        asm volatile("s_waitcnt vmcnt(2)" ::: "memory");  // step-t tile landed
      } else {
        asm volatile("s_waitcnt vmcnt(0)" ::: "memory");
      }
      __builtin_amdgcn_s_barrier();

      const char* AB = (const char*)(&A_lds[cur][0]);
      int dh = rr2 / 3, dw = rr2 - 3 * dh;
      int pofs = dh * 32 + dw;
      bf16x8 af[4], bfv[2];
#pragma unroll
      for (int mi = 0; mi < 4; mi++) {
        int row = wr * 64 + mi * 16 + colc;
        af[mi] = *(const bf16x8*)(AB + row * 64 + ((kg * 16) ^ asw));
      }
#pragma unroll
      for (int ni = 0; ni < 2; ni++) {
        int pix = pix0[ni] + pofs;
        bfv[ni] = *(const bf16x8*)(XF + pix * 256 + ((qt * 64 + kg * 16) ^ ((pix & 15) << 4)));
      }
      __builtin_amdgcn_s_setprio(1);
#pragma unroll
      for (int mi = 0; mi < 4; mi++)
#pragma unroll
        for (int ni = 0; ni < 2; ni++)
          acc[mi][ni] = __builtin_amdgcn_mfma_f32_16x16x32_bf16(
              af[mi], bfv[ni], acc[mi][ni], 0, 0, 0);
      __builtin_amdgcn_s_setprio(0);
      __builtin_amdgcn_s_barrier();   // all waves done with buf[cur] -> refill ok
    }
  }

  // ---- epilogue: transpose via Cst (aliases xfoot, now dead) ----
  float* Cst = (float*)xfoot;             // [128][64] f32 = 32 KB exactly
#pragma unroll
  for (int mi = 0; mi < 4; mi++) {
    int f0 = wr * 64 + mi * 16 + kg * 4;
#pragma unroll
    for (int ni = 0; ni < 2; ni++) {
      int cc = wc * 32 + ni * 16 + colc;
#pragma unroll
      for (int r = 0; r < 4; r++)
        Cst[(f0 + r) * 64 + cc] = acc[mi][ni][r];
    }
  }
  __syncthreads();
  {
    int col = tid & 63, fq = tid >> 6;
    if (col < BLT) {
      float xn = xn_s[col];
      float* ob = out + (size_t)n * (F_OUT * P_SP) + p0 + col;
#pragma unroll
      for (int q = 0; q < 32; q++) {
        int f = fq * 32 + q;
        __builtin_nontemporal_store(Cst[f * 64 + col] - wn_s[f] - xn, ob + f * P_SP);
      }
    }
  }
}

// ---------------------------------------------------------------------------
extern "C" void kernel_launch(void* const* d_in, const int* in_sizes, int n_in,
                              void* d_out, int out_size, void* d_ws, size_t ws_size,
                              hipStream_t stream) {
  const float* x = (const float*)d_in[0];
  const float* W = (const float*)d_in[1];
  float* out = (float*)d_out;

  char* ws = (char*)d_ws;
  unsigned short* Wbf = (unsigned short*)(ws);       // 294,912 B
  float* wnorm = (float*)(ws + 294912);              //     512 B

  prep_w_kernel<<<F_OUT, 256, 0, stream>>>(W, Wbf, wnorm);
  adder_fused_kernel<<<NBLK, 256, 0, stream>>>(x, Wbf, wnorm, out);
}

// Round 9
// 27.511 us; speedup vs baseline: 1.8717x; 1.2128x over previous
//
#include <hip/hip_runtime.h>
#include <hip/hip_bf16.h>
#include <stdint.h>

// out[n,f,i,j] = sum_k W[f,k]*patch[n,i,j,k] - 0.5||W_f||^2 - 0.5||X_{n,i,j}||^2
// x: (32,128,28,28) f32 ; W: (128,128,3,3) f32 ; out: (32,128,30,30) f32
// pad=2, ho=wo=30, L=28800, K=1152, F=128

#define N_IMG 32
#define C_IN 128
#define H_IN 28
#define HP 32
#define HO 30
#define P_SP 900
#define F_OUT 128
#define K_TOT 1152

#define BLT 60              // L-tile: 2 raster rows, no image crossing
#define TPI 15              // tiles per image
#define NBLK (N_IMG*TPI)    // 480 blocks (1.875/CU resident; 2/CU capacity)
#define NSTEP 18            // K steps of BK=64 (9 window positions x 2 halves)

typedef __attribute__((ext_vector_type(8))) short bf16x8;
typedef __attribute__((ext_vector_type(4))) unsigned short u16x4;
typedef __attribute__((ext_vector_type(8))) unsigned short u16x8;
typedef __attribute__((ext_vector_type(4))) float f32x4;

__device__ __forceinline__ unsigned short f2bf(float f) {
  union { float f; unsigned u; } t; t.f = f;
  unsigned r = t.u + 0x7fffu + ((t.u >> 16) & 1u);
  return (unsigned short)(r >> 16);
}

// ---------------------------------------------------------------------------
// Kernel 1 (tiny): W -> bf16 reordered k' = rr*128 + ch, + wnorm = 0.5||W_f||^2
// ---------------------------------------------------------------------------
__global__ void prep_w_kernel(const float* __restrict__ W,
                              unsigned short* __restrict__ Wbf,
                              float* __restrict__ wnorm) {
  int f = blockIdx.x;
  const float* Wf = W + f * K_TOT;
  float part = 0.f;
  for (int k = threadIdx.x; k < K_TOT; k += 256) {
    float v = Wf[k];                 // k = ch*9 + rr
    part += v * v;
    int ch = k / 9, rr = k - ch * 9;
    Wbf[f * K_TOT + rr * 128 + ch] = f2bf(v);
  }
  __shared__ float red[256];
  red[threadIdx.x] = part;
  __syncthreads();
  for (int st = 128; st > 0; st >>= 1) {
    if (threadIdx.x < st) red[threadIdx.x] += red[threadIdx.x + st];
    __syncthreads();
  }
  if (threadIdx.x == 0) wnorm[f] = 0.5f * red[0];
}

// ---------------------------------------------------------------------------
// Kernel 2: fused x-prep + implicit-im2col GEMM (r5 structure + counted vmcnt
// + XCD-chunked block remap).
//  - xfoot: block's unique x pixels (4 padded rows x 32 x 128c) LDS bf16,
//    swizzle byte ^= ((pix&15)<<4); all 9x window reuse from LDS.
//  - A-stream: BK=64 tiles (16 KB), double-buffered global_load_lds.
//    Loop: compute(t) -> barrier -> STAGE(t+2 -> just-freed buf) ->
//    s_waitcnt vmcnt(4) (waits STAGE(t+1) only; t+2's 4 stay in flight) ->
//    barrier. No mid-loop drain-to-0 (removes ~L2-latency/step stall).
//  - Block remap (bid&7)*60 + bid>>3: each XCD owns 4 whole images ->
//    adjacent tiles' 2-row x overlap hits that XCD's L2.
// ---------------------------------------------------------------------------
__global__ __launch_bounds__(256, 2) void adder_fused_kernel(
    const float* __restrict__ x,
    const unsigned short* __restrict__ Wbf,
    const float* __restrict__ wnorm,
    float* __restrict__ out) {
  __shared__ unsigned short xfoot[128 * 128];   // 32 KB
  __shared__ unsigned short A_lds[2][64 * 128]; // 2 x 16 KB (128 rows x 128 B)
  __shared__ float pixsum_s[128];
  __shared__ float xn_s[64];
  __shared__ float wn_s[F_OUT];

  int tid = threadIdx.x, lane = tid & 63, wid = tid >> 6;
  int bid0 = blockIdx.x;
  int bid = (bid0 & 7) * (NBLK / 8) + (bid0 >> 3);   // XCD-chunked, bijective
  int n = bid / TPI, timg = bid - n * TPI;
  int i0 = timg * 2, p0 = timg * BLT;

  char* XF = (char*)xfoot;
  char* A0 = (char*)&A_lds[0][0];
  char* A1 = (char*)&A_lds[1][0];
  const char* WbfB = (const char*)Wbf;

  // ---- A staging addresses (chunk = 1KB = 8 rows x 128B) ----
  int kb = ((lane & 7) * 16) ^ ((lane >> 3) << 4);  // pre-swizzled source byte
  int a_goff[4];
#pragma unroll
  for (int a = 0; a < 4; a++) {
    int q = a * 4 + wid;                  // 0..15
    int rowf = q * 8 + (lane >> 3);       // 0..127
    a_goff[a] = rowf * (K_TOT * 2) + kb;  // + t*128 per K-step
  }
  int a_loff = wid * 1024 + lane * 16;

  auto STAGE = [&](int t, char* AB) {
    int off = t * 128;
#pragma unroll
    for (int a = 0; a < 4; a++)
      __builtin_amdgcn_global_load_lds(
          (const __attribute__((address_space(1))) void*)(WbfB + a_goff[a] + off),
          (__attribute__((address_space(3))) void*)(AB + a * 4096 + a_loff), 16, 0, 0);
  };

  // ---- prologue: wn load + A(0),A(1) DMA, then build xfoot ----
  if (tid < F_OUT) wn_s[tid] = wnorm[tid];
  STAGE(0, A0);
  STAGE(1, A1);

  // x conversion: 4 padded rows (hr = i0-2+r), channels-last bf16, swizzled.
  for (int u = tid; u < 896; u += 256) {
    int r = u / 224, rem = u - r * 224;
    int w4 = rem >> 5, cq = rem & 31, c = cq * 4;
    int hr = i0 - 2 + r;
    float vv[4][4];
    if (hr >= 0 && hr < H_IN) {
#pragma unroll
      for (int q = 0; q < 4; q++) {
        float4 t4 = *(const float4*)(x + (((n * C_IN + c + q) * H_IN + hr) * H_IN + w4 * 4));
        vv[q][0] = t4.x; vv[q][1] = t4.y; vv[q][2] = t4.z; vv[q][3] = t4.w;
      }
    } else {
#pragma unroll
      for (int q = 0; q < 4; q++)
#pragma unroll
        for (int e = 0; e < 4; e++) vv[q][e] = 0.f;
    }
#pragma unroll
    for (int e = 0; e < 4; e++) {
      int wp = w4 * 4 + e + 2;            // 2..29
      int pix = r * 32 + wp;
      u16x4 o;
#pragma unroll
      for (int q = 0; q < 4; q++) o[q] = f2bf(vv[q][e]);
      *(u16x4*)(XF + pix * 256 + ((c * 2) ^ ((pix & 15) << 4))) = o;
    }
  }
  // border zeros: wp in {0,1,30,31} for all 4 rows
  {
    int r = tid >> 6, wi = (tid >> 4) & 3, slot = tid & 15;
    int wp = (wi < 2) ? wi : 28 + wi;     // 0,1,30,31
    int pix = r * 32 + wp;
    u16x8 z;
#pragma unroll
    for (int q = 0; q < 8; q++) z[q] = 0;
    *(u16x8*)(XF + pix * 256 + ((slot * 16) ^ ((pix & 15) << 4))) = z;
  }
  __syncthreads();

  // per-pixel squared channel sums (2 threads per pixel)
  {
    int pix = tid >> 1, ch = tid & 1;
    float ssum = 0.f;
#pragma unroll
    for (int q = 0; q < 8; q++) {
      u16x8 v8 = *(const u16x8*)(XF + pix * 256 + (((ch * 128) + q * 16) ^ ((pix & 15) << 4)));
#pragma unroll
      for (int e = 0; e < 8; e++) {
        union { unsigned u; float f; } cv; cv.u = ((unsigned)v8[e]) << 16;
        ssum += cv.f * cv.f;
      }
    }
    ssum += __shfl_xor(ssum, 1);
    if (!ch) pixsum_s[pix] = ssum;
  }
  __syncthreads();
  if (tid < BLT) {
    int il = tid / HO, j = tid - il * HO;
    float a9 = 0.f;
#pragma unroll
    for (int dh = 0; dh < 3; dh++)
#pragma unroll
      for (int dw = 0; dw < 3; dw++)
        a9 += pixsum_s[(il + dh) * 32 + (j + dw)];
    xn_s[tid] = 0.5f * a9;
  }
  __syncthreads();   // full drain: A(0), A(1) landed; xfoot/xn_s visible

  // ---- K-loop ----
  f32x4 acc[4][2];
#pragma unroll
  for (int mi = 0; mi < 4; mi++)
#pragma unroll
    for (int ni = 0; ni < 2; ni++)
      acc[mi][ni] = (f32x4){0.f, 0.f, 0.f, 0.f};

  int wr = wid >> 1, wc = wid & 1;
  int pix0[2];
#pragma unroll
  for (int ni = 0; ni < 2; ni++) {
    int cc = wc * 32 + ni * 16 + (lane & 15);
    if (cc > BLT - 1) cc = BLT - 1;       // dead cols: valid reads, dropped later
    int il = cc / HO, j = cc - il * HO;
    pix0[ni] = il * 32 + j;
  }
  int kfrag = (lane >> 4) * 16;

#pragma unroll 2
  for (int t = 0; t < NSTEP; t++) {
    char* ABc = (t & 1) ? A1 : A0;
    int rr = t >> 1, half = t & 1;
    int dh = rr / 3, dw = rr - 3 * dh;
    int pofs = dh * 32 + dw;
    int bbase = half * 128;
#pragma unroll
    for (int kc = 0; kc < 2; kc++) {
      bf16x8 af[4], bfv[2];
#pragma unroll
      for (int mi = 0; mi < 4; mi++) {
        int rowf = wr * 64 + mi * 16 + (lane & 15);
        af[mi] = *(const bf16x8*)(ABc + rowf * 128 + ((kc * 64 + kfrag) ^ ((rowf & 7) << 4)));
      }
#pragma unroll
      for (int ni = 0; ni < 2; ni++) {
        int pix = pix0[ni] + pofs;
        bfv[ni] = *(const bf16x8*)(XF + pix * 256 + ((bbase + kc * 64 + kfrag) ^ ((pix & 15) << 4)));
      }
      __builtin_amdgcn_s_setprio(1);
#pragma unroll
      for (int mi = 0; mi < 4; mi++)
#pragma unroll
        for (int ni = 0; ni < 2; ni++)
          acc[mi][ni] = __builtin_amdgcn_mfma_f32_16x16x32_bf16(
              af[mi], bfv[ni], acc[mi][ni], 0, 0, 0);
      __builtin_amdgcn_s_setprio(0);
    }
    // readers of buf[cur] done (lgkm forced by MFMA consumption)
    __builtin_amdgcn_s_barrier();
    if (t + 2 < NSTEP) {
      STAGE(t + 2, ABc);                               // refill just-freed buf
      asm volatile("s_waitcnt vmcnt(4)" ::: "memory");  // STAGE(t+1) landed;
      __builtin_amdgcn_s_barrier();                     // t+2's 4 stay in flight
    } else if (t + 2 == NSTEP) {
      asm volatile("s_waitcnt vmcnt(0)" ::: "memory");  // tail: STAGE(17) landed
      __builtin_amdgcn_s_barrier();
    }
  }

  // ---- epilogue: fused norms, direct stores (16-lane x 4B = 64B segments) ----
#pragma unroll
  for (int ni = 0; ni < 2; ni++) {
    int cc = wc * 32 + ni * 16 + (lane & 15);
    if (cc < BLT) {
      float xn = xn_s[cc];
      float* ob = out + (size_t)n * (F_OUT * P_SP) + p0 + cc;
#pragma unroll
      for (int mi = 0; mi < 4; mi++) {
        int f0 = wr * 64 + mi * 16 + (lane >> 4) * 4;
#pragma unroll
        for (int r2 = 0; r2 < 4; r2++) {
          int f = f0 + r2;
          ob[f * P_SP] = acc[mi][ni][r2] - wn_s[f] - xn;
        }
      }
    }
  }
}

// ---------------------------------------------------------------------------
extern "C" void kernel_launch(void* const* d_in, const int* in_sizes, int n_in,
                              void* d_out, int out_size, void* d_ws, size_t ws_size,
                              hipStream_t stream) {
  const float* x = (const float*)d_in[0];
  const float* W = (const float*)d_in[1];
  float* out = (float*)d_out;

  char* ws = (char*)d_ws;
  unsigned short* Wbf = (unsigned short*)(ws);       // 294,912 B
  float* wnorm = (float*)(ws + 294912);              //     512 B

  prep_w_kernel<<<F_OUT, 256, 0, stream>>>(W, Wbf, wnorm);
  adder_fused_kernel<<<NBLK, 256, 0, stream>>>(x, Wbf, wnorm, out);
}

// Round 10
// 26.866 us; speedup vs baseline: 1.9166x; 1.0240x over previous
//
#include <hip/hip_runtime.h>
#include <hip/hip_bf16.h>
#include <stdint.h>

// out[n,f,i,j] = sum_k W[f,k]*patch[n,i,j,k] - 0.5||W_f||^2 - 0.5||X_{n,i,j}||^2
// x: (32,128,28,28) f32 ; W: (128,128,3,3) f32 ; out: (32,128,30,30) f32
// pad=2, ho=wo=30, L=28800, K=1152, F=128

#define N_IMG 32
#define C_IN 128
#define H_IN 28
#define HP 32
#define HO 30
#define P_SP 900
#define F_OUT 128
#define K_TOT 1152

#define BLT 60              // L-tile: 2 raster rows, no image crossing
#define TPI 15              // tiles per image
#define NBLK (N_IMG*TPI)    // 480 blocks (2/CU capacity; ~67 KB LDS)
#define NSTEP 18            // K steps of BK=64 (9 window positions x 2 halves)

typedef __attribute__((ext_vector_type(8))) short bf16x8;
typedef __attribute__((ext_vector_type(4))) unsigned short u16x4;
typedef __attribute__((ext_vector_type(8))) unsigned short u16x8;
typedef __attribute__((ext_vector_type(4))) float f32x4;

__device__ __forceinline__ unsigned short f2bf(float f) {
  union { float f; unsigned u; } t; t.f = f;
  unsigned r = t.u + 0x7fffu + ((t.u >> 16) & 1u);
  return (unsigned short)(r >> 16);
}

// ---------------------------------------------------------------------------
// Kernel 1 (tiny): W -> bf16 reordered k' = rr*128 + ch, + wnorm = 0.5||W_f||^2
// ---------------------------------------------------------------------------
__global__ void prep_w_kernel(const float* __restrict__ W,
                              unsigned short* __restrict__ Wbf,
                              float* __restrict__ wnorm) {
  int f = blockIdx.x;
  const float* Wf = W + f * K_TOT;
  float part = 0.f;
  for (int k = threadIdx.x; k < K_TOT; k += 256) {
    float v = Wf[k];                 // k = ch*9 + rr
    part += v * v;
    int ch = k / 9, rr = k - ch * 9;
    Wbf[f * K_TOT + rr * 128 + ch] = f2bf(v);
  }
  __shared__ float red[256];
  red[threadIdx.x] = part;
  __syncthreads();
  for (int st = 128; st > 0; st >>= 1) {
    if (threadIdx.x < st) red[threadIdx.x] += red[threadIdx.x + st];
    __syncthreads();
  }
  if (threadIdx.x == 0) wnorm[f] = 0.5f * red[0];
}

// ---------------------------------------------------------------------------
// Kernel 2: fused x-prep + implicit-im2col GEMM (r9 + coalesced x-load +
// coalesced epilogue).
//  - x-conversion lane map: u = cq*28 + r*7 + w4 -> consecutive lanes sweep
//    (r,w4) within one channel row => wave reads ~9 contiguous 112-B runs
//    (was: 64 distinct lines/instr, ~4x over-fetch).
//  - xfoot: 4 padded rows x 32 wp x 128 c bf16, swizzle byte^=((pix&15)<<4).
//    Widened to 128*130 u16 so the epilogue Cst alias gets stride-65 f32
//    (conflict-free transpose).
//  - A-stream: BK=64 double-buffered global_load_lds; counted vmcnt(4);
//    2 barriers/step; XCD-chunked block remap. All r9-verbatim.
//  - Epilogue: acc -> Cst (65-stride, aliases xfoot after barrier) ->
//    240-B coalesced nontemporal stores, fused -wnorm[f] - 0.5||X||^2.
// ---------------------------------------------------------------------------
__global__ __launch_bounds__(256, 2) void adder_fused_kernel(
    const float* __restrict__ x,
    const unsigned short* __restrict__ Wbf,
    const float* __restrict__ wnorm,
    float* __restrict__ out) {
  __shared__ unsigned short xfoot[128 * 130];   // 33280 B (pix*256 B used + pad)
  __shared__ unsigned short A_lds[2][64 * 128]; // 2 x 16 KB (128 rows x 128 B)
  __shared__ float pixsum_s[128];
  __shared__ float xn_s[64];
  __shared__ float wn_s[F_OUT];

  int tid = threadIdx.x, lane = tid & 63, wid = tid >> 6;
  int bid0 = blockIdx.x;
  int bid = (bid0 & 7) * (NBLK / 8) + (bid0 >> 3);   // XCD-chunked, bijective
  int n = bid / TPI, timg = bid - n * TPI;
  int i0 = timg * 2, p0 = timg * BLT;

  char* XF = (char*)xfoot;
  char* A0 = (char*)&A_lds[0][0];
  char* A1 = (char*)&A_lds[1][0];
  const char* WbfB = (const char*)Wbf;

  // ---- A staging addresses (chunk = 1KB = 8 rows x 128B) ----
  int kb = ((lane & 7) * 16) ^ ((lane >> 3) << 4);  // pre-swizzled source byte
  int a_goff[4];
#pragma unroll
  for (int a = 0; a < 4; a++) {
    int q = a * 4 + wid;                  // 0..15
    int rowf = q * 8 + (lane >> 3);       // 0..127
    a_goff[a] = rowf * (K_TOT * 2) + kb;  // + t*128 per K-step
  }
  int a_loff = wid * 1024 + lane * 16;

  auto STAGE = [&](int t, char* AB) {
    int off = t * 128;
#pragma unroll
    for (int a = 0; a < 4; a++)
      __builtin_amdgcn_global_load_lds(
          (const __attribute__((address_space(1))) void*)(WbfB + a_goff[a] + off),
          (__attribute__((address_space(3))) void*)(AB + a * 4096 + a_loff), 16, 0, 0);
  };

  // ---- prologue: wn load + A(0),A(1) DMA, then build xfoot ----
  if (tid < F_OUT) wn_s[tid] = wnorm[tid];
  STAGE(0, A0);
  STAGE(1, A1);

  // x conversion, coalesced mapping: u = cq*28 + r*7 + w4.
  for (int u = tid; u < 896; u += 256) {
    int cq = u / 28, rem = u - cq * 28;
    int r = rem / 7, w4 = rem - r * 7;
    int c = cq * 4;
    int hr = i0 - 2 + r;
    float vv[4][4];
    if (hr >= 0 && hr < H_IN) {
#pragma unroll
      for (int q = 0; q < 4; q++) {
        float4 t4 = *(const float4*)(x + (((n * C_IN + c + q) * H_IN + hr) * H_IN + w4 * 4));
        vv[q][0] = t4.x; vv[q][1] = t4.y; vv[q][2] = t4.z; vv[q][3] = t4.w;
      }
    } else {
#pragma unroll
      for (int q = 0; q < 4; q++)
#pragma unroll
        for (int e = 0; e < 4; e++) vv[q][e] = 0.f;
    }
#pragma unroll
    for (int e = 0; e < 4; e++) {
      int wp = w4 * 4 + e + 2;            // 2..29
      int pix = r * 32 + wp;
      u16x4 o;
#pragma unroll
      for (int q = 0; q < 4; q++) o[q] = f2bf(vv[q][e]);
      *(u16x4*)(XF + pix * 256 + ((c * 2) ^ ((pix & 15) << 4))) = o;
    }
  }
  // border zeros: wp in {0,1,30,31} for all 4 rows
  {
    int r = tid >> 6, wi = (tid >> 4) & 3, slot = tid & 15;
    int wp = (wi < 2) ? wi : 28 + wi;     // 0,1,30,31
    int pix = r * 32 + wp;
    u16x8 z;
#pragma unroll
    for (int q = 0; q < 8; q++) z[q] = 0;
    *(u16x8*)(XF + pix * 256 + ((slot * 16) ^ ((pix & 15) << 4))) = z;
  }
  __syncthreads();

  // per-pixel squared channel sums (2 threads per pixel)
  {
    int pix = tid >> 1, ch = tid & 1;
    float ssum = 0.f;
#pragma unroll
    for (int q = 0; q < 8; q++) {
      u16x8 v8 = *(const u16x8*)(XF + pix * 256 + (((ch * 128) + q * 16) ^ ((pix & 15) << 4)));
#pragma unroll
      for (int e = 0; e < 8; e++) {
        union { unsigned u; float f; } cv; cv.u = ((unsigned)v8[e]) << 16;
        ssum += cv.f * cv.f;
      }
    }
    ssum += __shfl_xor(ssum, 1);
    if (!ch) pixsum_s[pix] = ssum;
  }
  __syncthreads();
  if (tid < BLT) {
    int il = tid / HO, j = tid - il * HO;
    float a9 = 0.f;
#pragma unroll
    for (int dh = 0; dh < 3; dh++)
#pragma unroll
      for (int dw = 0; dw < 3; dw++)
        a9 += pixsum_s[(il + dh) * 32 + (j + dw)];
    xn_s[tid] = 0.5f * a9;
  }
  __syncthreads();   // full drain: A(0), A(1) landed; xfoot/xn_s visible

  // ---- K-loop (r9-verbatim) ----
  f32x4 acc[4][2];
#pragma unroll
  for (int mi = 0; mi < 4; mi++)
#pragma unroll
    for (int ni = 0; ni < 2; ni++)
      acc[mi][ni] = (f32x4){0.f, 0.f, 0.f, 0.f};

  int wr = wid >> 1, wc = wid & 1;
  int pix0[2];
#pragma unroll
  for (int ni = 0; ni < 2; ni++) {
    int cc = wc * 32 + ni * 16 + (lane & 15);
    if (cc > BLT - 1) cc = BLT - 1;       // dead cols: valid reads, dropped later
    int il = cc / HO, j = cc - il * HO;
    pix0[ni] = il * 32 + j;
  }
  int kfrag = (lane >> 4) * 16;

#pragma unroll 2
  for (int t = 0; t < NSTEP; t++) {
    char* ABc = (t & 1) ? A1 : A0;
    int rr = t >> 1, half = t & 1;
    int dh = rr / 3, dw = rr - 3 * dh;
    int pofs = dh * 32 + dw;
    int bbase = half * 128;
#pragma unroll
    for (int kc = 0; kc < 2; kc++) {
      bf16x8 af[4], bfv[2];
#pragma unroll
      for (int mi = 0; mi < 4; mi++) {
        int rowf = wr * 64 + mi * 16 + (lane & 15);
        af[mi] = *(const bf16x8*)(ABc + rowf * 128 + ((kc * 64 + kfrag) ^ ((rowf & 7) << 4)));
      }
#pragma unroll
      for (int ni = 0; ni < 2; ni++) {
        int pix = pix0[ni] + pofs;
        bfv[ni] = *(const bf16x8*)(XF + pix * 256 + ((bbase + kc * 64 + kfrag) ^ ((pix & 15) << 4)));
      }
      __builtin_amdgcn_s_setprio(1);
#pragma unroll
      for (int mi = 0; mi < 4; mi++)
#pragma unroll
        for (int ni = 0; ni < 2; ni++)
          acc[mi][ni] = __builtin_amdgcn_mfma_f32_16x16x32_bf16(
              af[mi], bfv[ni], acc[mi][ni], 0, 0, 0);
      __builtin_amdgcn_s_setprio(0);
    }
    __builtin_amdgcn_s_barrier();
    if (t + 2 < NSTEP) {
      STAGE(t + 2, ABc);                               // refill just-freed buf
      asm volatile("s_waitcnt vmcnt(4)" ::: "memory");  // STAGE(t+1) landed
      __builtin_amdgcn_s_barrier();                     // t+2's 4 stay in flight
    } else if (t + 2 == NSTEP) {
      asm volatile("s_waitcnt vmcnt(0)" ::: "memory");  // tail: STAGE(17) landed
      __builtin_amdgcn_s_barrier();
    }
  }
  __syncthreads();   // step-17 xfoot B-reads done before Cst alias writes

  // ---- epilogue: acc -> Cst (stride 65, aliases xfoot) -> coalesced stores ----
  float* Cst = (float*)xfoot;             // [128][65] f32 = 33280 B exactly
  int colc = lane & 15, kg = lane >> 4;
#pragma unroll
  for (int mi = 0; mi < 4; mi++) {
    int f0 = wr * 64 + mi * 16 + kg * 4;
#pragma unroll
    for (int ni = 0; ni < 2; ni++) {
      int cc = wc * 32 + ni * 16 + colc;
#pragma unroll
      for (int r = 0; r < 4; r++)
        Cst[(f0 + r) * 65 + cc] = acc[mi][ni][r];
    }
  }
  __syncthreads();
  {
    int col = tid & 63, fq = tid >> 6;
    if (col < BLT) {
      float xn = xn_s[col];
      float* ob = out + (size_t)n * (F_OUT * P_SP) + p0 + col;
#pragma unroll
      for (int q = 0; q < 32; q++) {
        int f = fq * 32 + q;
        __builtin_nontemporal_store(Cst[f * 65 + col] - wn_s[f] - xn, ob + f * P_SP);
      }
    }
  }
}

// ---------------------------------------------------------------------------
extern "C" void kernel_launch(void* const* d_in, const int* in_sizes, int n_in,
                              void* d_out, int out_size, void* d_ws, size_t ws_size,
                              hipStream_t stream) {
  const float* x = (const float*)d_in[0];
  const float* W = (const float*)d_in[1];
  float* out = (float*)d_out;

  char* ws = (char*)d_ws;
  unsigned short* Wbf = (unsigned short*)(ws);       // 294,912 B
  float* wnorm = (float*)(ws + 294912);              //     512 B

  prep_w_kernel<<<F_OUT, 256, 0, stream>>>(W, Wbf, wnorm);
  adder_fused_kernel<<<NBLK, 256, 0, stream>>>(x, Wbf, wnorm, out);
}